// Round 3
// baseline (8882.956 us; speedup 1.0000x reference)
//
#include <hip/hip_runtime.h>

typedef unsigned short u16;
typedef unsigned int u32;
typedef __attribute__((ext_vector_type(8))) short short8;   // 8 bf16 = 4 VGPRs (MFMA A/B frag)
typedef __attribute__((ext_vector_type(4))) float f32x4;    // MFMA C/D frag

#define NB 32
#define TE 512
#define LD 128
#define NBLK 128

__device__ __forceinline__ float bfl(u32 u){ return __uint_as_float(u << 16); }
__device__ __forceinline__ float bfh(u32 u){ return __uint_as_float(u & 0xffff0000u); }
__device__ __forceinline__ float bf1(u16 v){ return __uint_as_float(((u32)v) << 16); }
__device__ __forceinline__ u16 f2bf(float f){
  u32 x = __float_as_uint(f);
  return (u16)((x + 0x7fffu + ((x >> 16) & 1u)) >> 16);
}
__device__ __forceinline__ float sigf(float x){ return 1.0f / (1.0f + __expf(-x)); }

// device-scope sense barrier: one release-add + acquire-spin per block (thread 0).
__device__ __forceinline__ void gbar(u32* bar, u32* bc){
  __syncthreads();
  *bc += 1;
  if (threadIdx.x == 0){
    __hip_atomic_fetch_add(bar, 1u, __ATOMIC_RELEASE, __HIP_MEMORY_SCOPE_AGENT);
    u32 target = *bc * NBLK;
    while (__hip_atomic_load(bar, __ATOMIC_RELAXED, __HIP_MEMORY_SCOPE_AGENT) < target){
      __builtin_amdgcn_s_sleep(1);
    }
    (void)__hip_atomic_load(bar, __ATOMIC_ACQUIRE, __HIP_MEMORY_SCOPE_AGENT);
  }
  __syncthreads();
}

// ================= one-time prep: fused bf16 hi/lo weights + bias sums ==========
__global__ void k_prep(
    const float* __restrict__ Wih1, const float* __restrict__ Whh1,
    const float* __restrict__ bih1, const float* __restrict__ bhh1,
    const float* __restrict__ Wih2, const float* __restrict__ Whh2,
    const float* __restrict__ bih2, const float* __restrict__ bhh2,
    u16* __restrict__ w1hi, u16* __restrict__ w1lo,
    u16* __restrict__ w2hi, u16* __restrict__ w2lo,
    float* __restrict__ bias1, float* __restrict__ bias2,
    u32* __restrict__ bar)
{
  int idx = blockIdx.x * 256 + threadIdx.x;
  if (idx == 0) *bar = 0u;
  if (idx < 5767168){                       // 4096*1408
    int j = idx / 1408, c = idx - j * 1408;
    float v = (c < 384) ? Wih1[(size_t)j * 384 + c] : Whh1[(size_t)j * 1024 + (c - 384)];
    u16 h = f2bf(v);
    w1hi[idx] = h;
    w1lo[idx] = f2bf(v - bf1(h));
    return;
  }
  idx -= 5767168;
  if (idx < 589824){                        // 512*1152
    int j = idx / 1152, c = idx - j * 1152;
    float v = (c < 1024) ? Wih2[(size_t)j * 1024 + c] : Whh2[(size_t)j * 128 + (c - 1024)];
    u16 h = f2bf(v);
    w2hi[idx] = h;
    w2lo[idx] = f2bf(v - bf1(h));
    return;
  }
  idx -= 589824;
  if (idx < 4096){ bias1[idx] = bih1[idx] + bhh1[idx]; return; }
  idx -= 4096;
  if (idx < 512){ bias2[idx] = bih2[idx] + bhh2[idx]; }
}

// ================= persistent kernel: the whole 128-step decode loop ============
// 128 blocks x 256 threads, cooperative. 3 grid barriers per step.
// xb (DOUBLE-BUFFERED, 45056 u16 each) = [emb(256) | ctx(128) | h1(1024)] per row.
// Phase 1 at step t reads xb[t&1]; cell1(h1) and phase-3(emb,ctx) write xb[(t+1)&1].
// xb2 = [h1(1024) | h2(128)] bf16 per batch row (stride 1152), single buffer (no race:
// every writer/reader pair is separated by a gbar).
__global__ __launch_bounds__(256) void k_persist(
    const float* __restrict__ key, const float* __restrict__ values,
    const int* __restrict__ elen, const int* __restrict__ text,
    const float* __restrict__ emb,
    const u16* __restrict__ w1hi, const u16* __restrict__ w1lo,
    const u16* __restrict__ w2hi, const u16* __restrict__ w2lo,
    const float* __restrict__ bias1, const float* __restrict__ bias2,
    u16* __restrict__ xbA, u16* __restrict__ xbB, u16* __restrict__ xb2,
    float* __restrict__ c1, float* __restrict__ c2,
    float* __restrict__ gp2f, u16* __restrict__ aall,
    u32* __restrict__ bar)
{
  __shared__ float smem[2048];      // phase-overlaid scratch (8 KB)
  __shared__ float s_h2[128];
  __shared__ float s_red[4];
  int tid = threadIdx.x;
  int blk = blockIdx.x;
  int lane = tid & 63, wid = tid >> 6;
  u32 bc = 0;

  // ---- init: zero c1,c2, xb2; build xbA for t=0
  for (int idx = blk * 256 + tid; idx < 118784; idx += NBLK * 256){
    int i = idx;
    if (i < 32768){ c1[i] = 0.0f; continue; }
    i -= 32768;
    if (i < 4096){ c2[i] = 0.0f; continue; }
    i -= 4096;
    if (i < 45056){                          // 32*1408
      int n = i / 1408, c = i - n * 1408;
      u16 v = 0;
      if (c < 256)      v = f2bf(emb[256 + c]);                       // SOS token = 1
      else if (c < 384) v = f2bf(values[(size_t)n * TE * 128 + (c - 256)]);
      xbA[i] = v;
      continue;
    }
    i -= 45056;
    xb2[i] = 0;                              // h1=0, h2=0
  }
  gbar(bar, &bc);

  for (int t = 0; t < 128; t++){
    const u16* xr = (t & 1) ? xbB : xbA;     // input vector for this step
    u16* xw = (t & 1) ? xbA : xbB;           // input vector being built for t+1

    // ================= phase 1: gates1 + cell1 (all 128 blocks) ===============
    // block -> (unit-group g, batch-half h), XCD-swizzled so XCD x owns groups
    // [8x, 8x+8) both halves -> 2.9 MB weight slice stays in that XCD's L2.
    {
      int xg = blk & 7, sb = blk >> 3;
      int g = xg * 8 + (sb >> 1), h = sb & 1;
      int r = lane & 15, kb = lane >> 4;
      int row = wid * 1024 + g * 16 + r;       // wave = gate
      const short8* wh = (const short8*)w1hi + (size_t)row * 176 + kb;
      const short8* wl = (const short8*)w1lo + (size_t)row * 176 + kb;
      const short8* xa = (const short8*)xr + (size_t)(h * 16 + r) * 176 + kb;
      f32x4 acc = {0.f, 0.f, 0.f, 0.f};
      #pragma unroll 4
      for (int ss = 0; ss < 44; ss++){
        short8 a  = xa[4 * ss];
        short8 b0 = wh[4 * ss], b1 = wl[4 * ss];
        acc = __builtin_amdgcn_mfma_f32_16x16x32_bf16(a, b0, acc, 0, 0, 0);
        acc = __builtin_amdgcn_mfma_f32_16x16x32_bf16(a, b1, acc, 0, 0, 0);
      }
      #pragma unroll
      for (int q = 0; q < 4; q++){
        int nl = kb * 4 + q;                   // D row = batch (local)
        smem[wid * 256 + nl * 16 + r] = acc[q];
      }
      __syncthreads();
      // cell1: one (batch, unit) element per thread
      {
        int nl = tid >> 4, u = tid & 15;
        int uu = g * 16 + u;
        int n = h * 16 + nl;
        float gi = smem[tid]            + bias1[uu];
        float gf = smem[256 + tid]      + bias1[1024 + uu];
        float gg = smem[512 + tid]      + bias1[2048 + uu];
        float go = smem[768 + tid]      + bias1[3072 + uu];
        gi = sigf(gi); gf = sigf(gf); gg = tanhf(gg); go = sigf(go);
        int ci = n * 1024 + uu;
        float cn = gf * c1[ci] + gi * gg;
        c1[ci] = cn;
        float hn = go * tanhf(cn);
        u16 hb = f2bf(hn);
        xw[n * 1408 + 384 + uu] = hb;          // next step's input buffer
        xb2[n * 1152 + uu] = hb;               // read by phase 2 after gbar
      }
    }
    gbar(bar, &bc);

    // ================= phase 2: gates2 (blocks 0..31) =========================
    if (blk < 32){
      int rt = blk;
      int r = lane & 15, kb = lane >> 4;
      int row = rt * 16 + r;
      const short8* wh = (const short8*)w2hi + (size_t)row * 144 + wid * 36 + kb;
      const short8* wl = (const short8*)w2lo + (size_t)row * 144 + wid * 36 + kb;
      const short8* xa = (const short8*)xb2 + (size_t)r * 144 + wid * 36 + kb;
      const short8* xc = xa + 16 * 144;
      f32x4 acc0 = {0.f,0.f,0.f,0.f}, acc1 = {0.f,0.f,0.f,0.f};
      #pragma unroll
      for (int ss = 0; ss < 9; ss++){
        short8 a0 = xa[4 * ss], a1 = xc[4 * ss];
        short8 b0 = wh[4 * ss], b1 = wl[4 * ss];
        acc0 = __builtin_amdgcn_mfma_f32_16x16x32_bf16(a0, b0, acc0, 0, 0, 0);
        acc1 = __builtin_amdgcn_mfma_f32_16x16x32_bf16(a1, b0, acc1, 0, 0, 0);
        acc0 = __builtin_amdgcn_mfma_f32_16x16x32_bf16(a0, b1, acc0, 0, 0, 0);
        acc1 = __builtin_amdgcn_mfma_f32_16x16x32_bf16(a1, b1, acc1, 0, 0, 0);
      }
      #pragma unroll
      for (int q = 0; q < 4; q++){
        int nl = kb * 4 + q;
        smem[wid * 512 + nl * 16 + r] = acc0[q];
        smem[wid * 512 + (nl + 16) * 16 + r] = acc1[q];
      }
      __syncthreads();
      for (int i = tid; i < 512; i += 256){
        float s = smem[i] + smem[512 + i] + smem[1024 + i] + smem[1536 + i];
        int n = i >> 4, u = i & 15;
        gp2f[n * 512 + rt * 16 + u] = s;
      }
    }
    gbar(bar, &bc);

    // ================= phase 3: cell2 + attention (blocks 0..31) ==============
    if (blk < 32){
      int n = blk;
      float* s_e = smem;              // 512 floats
      float* s_part = smem + 512;     // 256 floats
      if (tid < 128){
        int u = tid;
        float g0 = gp2f[n * 512 + u]       + bias2[u];
        float g1 = gp2f[n * 512 + 128 + u] + bias2[128 + u];
        float g2 = gp2f[n * 512 + 256 + u] + bias2[256 + u];
        float g3 = gp2f[n * 512 + 384 + u] + bias2[384 + u];
        float gi = sigf(g0), gf = sigf(g1), gt = tanhf(g2), go = sigf(g3);
        int ci = n * 128 + u;
        float cn = gf * c2[ci] + gi * gt;
        c2[ci] = cn;
        float hn = go * tanhf(cn);
        s_h2[u] = hn;
        u16 hb = f2bf(hn);
        xb2[n * 1152 + 1024 + u] = hb;
        aall[((size_t)t * NB + n) * 256 + u] = hb;
      } else {
        // waves 2,3: next-token embedding into xw (x for step t+1)
        int c = (tid - 128) * 2;
        int tok = text[n * LD + t];
        xw[n * 1408 + c]     = f2bf(emb[(size_t)tok * 256 + c]);
        xw[n * 1408 + c + 1] = f2bf(emb[(size_t)tok * 256 + c + 1]);
      }
      __syncthreads();
      int el = elen[n];
      float e0 = 0.f, e1 = 0.f;
      const float4* k0 = (const float4*)(key + ((size_t)n * TE + tid) * 128);
      const float4* k1 = (const float4*)(key + ((size_t)n * TE + tid + 256) * 128);
      #pragma unroll 8
      for (int q = 0; q < 32; q++){
        float4 wa = k0[q], wb = k1[q];
        float h0 = s_h2[4*q], h1 = s_h2[4*q+1], h2 = s_h2[4*q+2], h3 = s_h2[4*q+3];
        e0 += wa.x*h0 + wa.y*h1 + wa.z*h2 + wa.w*h3;
        e1 += wb.x*h0 + wb.y*h1 + wb.z*h2 + wb.w*h3;
      }
      if (tid >= el)       e0 = -1e9f;
      if (tid + 256 >= el) e1 = -1e9f;
      float m = fmaxf(e0, e1);
      for (int off = 32; off > 0; off >>= 1) m = fmaxf(m, __shfl_xor(m, off));
      if (lane == 0) s_red[wid] = m;
      __syncthreads();
      m = fmaxf(fmaxf(s_red[0], s_red[1]), fmaxf(s_red[2], s_red[3]));
      float p0 = __expf(e0 - m), p1 = __expf(e1 - m);
      s_e[tid] = p0; s_e[tid + 256] = p1;
      float sm = p0 + p1;
      for (int off = 32; off > 0; off >>= 1) sm += __shfl_xor(sm, off);
      __syncthreads();                 // protect s_red reuse (everyone read m)
      if (lane == 0) s_red[wid] = sm;
      __syncthreads();
      float inv = 1.0f / (s_red[0] + s_red[1] + s_red[2] + s_red[3]);
      int v = tid & 127, ch = tid >> 7;
      const float* vb = values + ((size_t)n * TE + ch * 256) * 128 + v;
      float a = 0.f;
      #pragma unroll 4
      for (int q = 0; q < 256; q++) a += s_e[ch * 256 + q] * vb[(size_t)q * 128];
      s_part[ch * 128 + v] = a;
      __syncthreads();
      if (tid < 128){
        float cv = (s_part[tid] + s_part[128 + tid]) * inv;
        u16 cb = f2bf(cv);
        xw[n * 1408 + 256 + tid] = cb;
        aall[((size_t)t * NB + n) * 256 + 128 + tid] = cb;
      }
    }
    gbar(bar, &bc);
  }
}

// ================= output GEMM (unchanged, known-correct) =======================
__global__ __launch_bounds__(256) void k_out(
    const u16* __restrict__ aall, const float* __restrict__ wout,
    const float* __restrict__ bout, float* __restrict__ out)
{
  __shared__ __align__(16) u16 sA[128 * 136];
  __shared__ __align__(16) u16 sW[80 * 136];
  int tid = threadIdx.x;
  int vt = blockIdx.x, rt = blockIdx.y;
  int v0 = vt * 80, r0 = rt * 128;
  int rg = tid >> 4, vg = tid & 15;
  float acc[8][5];
  #pragma unroll
  for (int i = 0; i < 8; i++)
    #pragma unroll
    for (int j = 0; j < 5; j++) acc[i][j] = 0.0f;
  for (int kc = 0; kc < 2; kc++){
    int k0 = kc * 128;
    __syncthreads();
    for (int i = tid; i < 128 * 128; i += 256){
      int r = i >> 7, c = i & 127;
      sA[r * 136 + c] = aall[((size_t)(r0 + r)) * 256 + k0 + c];
    }
    for (int i = tid; i < 80 * 128; i += 256){
      int r = i >> 7, c = i & 127;
      sW[r * 136 + c] = f2bf(wout[((size_t)(v0 + r)) * 256 + k0 + c]);
    }
    __syncthreads();
    const u16* ap = sA + (rg * 8) * 136;
    const u16* wp = sW + (vg * 5) * 136;
    for (int kp = 0; kp < 64; kp++){
      u32 av[8], wv[5];
      #pragma unroll
      for (int i = 0; i < 8; i++) av[i] = *(const u32*)(ap + i * 136 + 2 * kp);
      #pragma unroll
      for (int j = 0; j < 5; j++) wv[j] = *(const u32*)(wp + j * 136 + 2 * kp);
      float wlo[5], whi[5];
      #pragma unroll
      for (int j = 0; j < 5; j++){ wlo[j] = bfl(wv[j]); whi[j] = bfh(wv[j]); }
      #pragma unroll
      for (int i = 0; i < 8; i++){
        float a0 = bfl(av[i]), a1 = bfh(av[i]);
        #pragma unroll
        for (int j = 0; j < 5; j++) acc[i][j] += a0 * wlo[j] + a1 * whi[j];
      }
    }
  }
  #pragma unroll
  for (int i = 0; i < 8; i++){
    int r = r0 + rg * 8 + i;
    int tt = r >> 5, nn = r & 31;
    size_t ob = ((size_t)nn * LD + tt) * 8000 + v0 + vg * 5;
    #pragma unroll
    for (int j = 0; j < 5; j++){
      out[ob + j] = acc[i][j] + bout[v0 + vg * 5 + j];
    }
  }
}

extern "C" void kernel_launch(void* const* d_in, const int* in_sizes, int n_in,
                              void* d_out, int out_size, void* d_ws, size_t ws_size,
                              hipStream_t stream)
{
  const float* key    = (const float*)d_in[0];
  const float* values = (const float*)d_in[1];
  const int*   elen   = (const int*)d_in[2];
  const int*   text   = (const int*)d_in[3];
  const float* emb    = (const float*)d_in[4];
  const float* Wih1   = (const float*)d_in[5];
  const float* Whh1   = (const float*)d_in[6];
  const float* bih1   = (const float*)d_in[7];
  const float* bhh1   = (const float*)d_in[8];
  const float* Wih2   = (const float*)d_in[9];
  const float* Whh2   = (const float*)d_in[10];
  const float* bih2   = (const float*)d_in[11];
  const float* bhh2   = (const float*)d_in[12];
  const float* Wout   = (const float*)d_in[13];
  const float* bout   = (const float*)d_in[14];
  float* out = (float*)d_out;
  float* ws = (float*)d_ws;

  // ---- persistent state in ws
  float* c1  = ws;                      // 32768
  float* c2  = c1 + 32768;              // 4096
  u16*  aall = (u16*)(c2 + 4096);       // 4096*256 u16 = 2 MB (consumed by k_out)
  u32*  bar  = (u32*)(aall + 4096 * 256);

  // ---- transient scratch in the tail of out (k_out overwrites all of out after)
  float* sc = out + 25600000;           // byte offset 102,400,000 (16B aligned)
  u16* w1hi = (u16*)sc;                 // 5,767,168
  u16* w1lo = w1hi + 5767168;           // 5,767,168
  u16* w2hi = w1lo + 5767168;           // 589,824
  u16* w2lo = w2hi + 589824;            // 589,824
  u16* xbA  = w2lo + 589824;            // 32*1408 = 45,056
  u16* xbB  = xbA + 45056;              // 45,056
  u16* xb2  = xbB + 45056;              // 32*1152 = 36,864
  float* bias1 = (float*)(xb2 + 36864); // 4096
  float* bias2 = bias1 + 4096;          // 512
  float* gp2f  = bias2 + 512;           // 32*512 = 16,384  (total ~24.7 MB < tail)

  k_prep<<<24850, 256, 0, stream>>>(Wih1, Whh1, bih1, bhh1, Wih2, Whh2, bih2, bhh2,
                                    w1hi, w1lo, w2hi, w2lo, bias1, bias2, bar);

  void* args[] = {
    (void*)&key, (void*)&values, (void*)&elen, (void*)&text, (void*)&emb,
    (void*)&w1hi, (void*)&w1lo, (void*)&w2hi, (void*)&w2lo,
    (void*)&bias1, (void*)&bias2,
    (void*)&xbA, (void*)&xbB, (void*)&xb2, (void*)&c1, (void*)&c2,
    (void*)&gp2f, (void*)&aall, (void*)&bar
  };
  hipLaunchCooperativeKernel((const void*)k_persist, dim3(NBLK), dim3(256),
                             args, 0, stream);

  k_out<<<dim3(100, 32), 256, 0, stream>>>(aall, Wout, bout, out);
}

// Round 4
// 8538.874 us; speedup vs baseline: 1.0403x; 1.0403x over previous
//
#include <hip/hip_runtime.h>

typedef unsigned short u16;
typedef unsigned int u32;
typedef __attribute__((ext_vector_type(8))) short short8;   // 8 bf16 = 4 VGPRs (MFMA A/B frag)
typedef __attribute__((ext_vector_type(4))) float f32x4;    // MFMA C/D frag

#define NB 32
#define TE 512
#define LD 128
#define NBLK 256
#define NTHR 512
// LDS layout (dynamic, 107.0 KB):
//   s_w1 : 45056 u16 (16 rows x 1408 x {hi,lo})   [0, 90112)
//   s_w2 :  4608 u16 (2 rows x 1152 x {hi,lo})    [90112, 99328)
//   scrA :  2048 f32                              [99328, 107520)
//   scrB :   512 f32                              [107520, 109568)
#define SMEM_BYTES 109568

__device__ __forceinline__ float bfl(u32 u){ return __uint_as_float(u << 16); }
__device__ __forceinline__ float bfh(u32 u){ return __uint_as_float(u & 0xffff0000u); }
__device__ __forceinline__ float bf1(u16 v){ return __uint_as_float(((u32)v) << 16); }
__device__ __forceinline__ u16 f2bf(float f){
  u32 x = __float_as_uint(f);
  return (u16)((x + 0x7fffu + ((x >> 16) & 1u)) >> 16);
}
__device__ __forceinline__ float sigf(float x){ return 1.0f / (1.0f + __expf(-x)); }

// device-scope sense barrier: one release-add + acquire-spin per block (thread 0).
__device__ __forceinline__ void gbar(u32* bar, u32* bc){
  __syncthreads();
  *bc += 1;
  if (threadIdx.x == 0){
    __hip_atomic_fetch_add(bar, 1u, __ATOMIC_RELEASE, __HIP_MEMORY_SCOPE_AGENT);
    u32 target = *bc * NBLK;
    while (__hip_atomic_load(bar, __ATOMIC_RELAXED, __HIP_MEMORY_SCOPE_AGENT) < target){
      __builtin_amdgcn_s_sleep(1);
    }
    (void)__hip_atomic_load(bar, __ATOMIC_ACQUIRE, __HIP_MEMORY_SCOPE_AGENT);
  }
  __syncthreads();
}

// ================= persistent kernel: whole decode loop, LDS-resident weights ===
// 256 blocks x 512 threads (1 block/CU). Block b owns:
//   gates1: units [4b, 4b+4) -> 16 w1 rows {gate*1024 + 4b + j}, LDS rows r=gate*4+j
//   gates2: rows {2b, 2b+1} of the 512 gates2 outputs
// xb (double-buffered) = [emb(256) | ctx(128) | h1(1024)] bf16, stride 1408.
// xb2 = [h1(1024) | h2(128)] bf16, stride 1152.
__global__ __launch_bounds__(NTHR, 1) void k_persist(
    const float* __restrict__ key, const float* __restrict__ values,
    const int* __restrict__ elen, const int* __restrict__ text,
    const float* __restrict__ emb,
    const float* __restrict__ Wih1, const float* __restrict__ Whh1,
    const float* __restrict__ bih1, const float* __restrict__ bhh1,
    const float* __restrict__ Wih2, const float* __restrict__ Whh2,
    const float* __restrict__ bih2, const float* __restrict__ bhh2,
    u16* __restrict__ xbA, u16* __restrict__ xbB, u16* __restrict__ xb2,
    float* __restrict__ c1, float* __restrict__ c2,
    float* __restrict__ gp2f, u16* __restrict__ aall,
    u32* __restrict__ bar)
{
  extern __shared__ __align__(16) char smem_raw[];
  u16* s_w1   = (u16*)smem_raw;                    // 45056 u16
  u16* s_w2   = (u16*)(smem_raw + 90112);          // 4608 u16
  float* scrA = (float*)(smem_raw + 99328);        // 2048 f32
  float* scrB = (float*)(smem_raw + 107520);       // 512 f32

  int tid = threadIdx.x;
  int blk = blockIdx.x;
  int lane = tid & 63, wid = tid >> 6;
  u32 bc = 0;

  // ---- load this block's weight slices into LDS (fp32 -> bf16 hi/lo) ----
  // w1: 16 rows x 1408. LDS u16 index (p*16+r)*1408 + c, XOR-swizzled by ((r&7)<<3)
  // so the MFMA ds_read_b128 (lane r stride 2816B) spreads across banks.
  for (int i = tid; i < 16 * 1408; i += NTHR){
    int r = i / 1408, c = i - r * 1408;
    int grow = (r >> 2) * 1024 + blk * 4 + (r & 3);
    float v = (c < 384) ? Wih1[(size_t)grow * 384 + c]
                        : Whh1[(size_t)grow * 1024 + (c - 384)];
    u16 h = f2bf(v);
    u16 l = f2bf(v - bf1(h));
    int sw = ((r & 7) << 3);
    s_w1[(r * 1408 + c) ^ sw] = h;
    s_w1[(((16 + r) * 1408) + c) ^ sw] = l;
  }
  // w2: 2 rows x 1152, plain layout (scalar broadcast reads later)
  for (int i = tid; i < 2 * 1152; i += NTHR){
    int r = i / 1152, c = i - r * 1152;
    int R = blk * 2 + r;
    float v = (c < 1024) ? Wih2[(size_t)R * 1024 + c]
                         : Whh2[(size_t)R * 128 + (c - 1024)];
    u16 h = f2bf(v);
    s_w2[r * 1152 + c] = h;
    s_w2[(2 + r) * 1152 + c] = f2bf(v - bf1(h));
  }

  // ---- global init: zero c1,c2,xb2; build xbA for t=0 ----
  {
    int idx = blk * NTHR + tid;       // 131072 threads >= 118784 elements
    int i = idx;
    if (i < 32768){ c1[i] = 0.0f; }
    else {
      i -= 32768;
      if (i < 4096){ c2[i] = 0.0f; }
      else {
        i -= 4096;
        if (i < 45056){                          // 32*1408
          int n = i / 1408, c = i - n * 1408;
          u16 v = 0;
          if (c < 256)      v = f2bf(emb[256 + c]);                       // SOS
          else if (c < 384) v = f2bf(values[(size_t)n * TE * 128 + (c - 256)]);
          xbA[i] = v;
        } else {
          i -= 45056;
          if (i < 36864) xb2[i] = 0;             // h1=0, h2=0
        }
      }
    }
  }
  gbar(bar, &bc);

  for (int t = 0; t < 128; t++){
    const u16* xr = (t & 1) ? xbB : xbA;     // input vector for this step
    u16* xw = (t & 1) ? xbA : xbB;           // input vector being built for t+1

    // ===== phase 1: gates1 (MFMA, weights in LDS) + cell1, all 256 blocks =====
    // wave (q = wid>>1, hh = wid&1): K-quarter q (11 chunks of 32), batch-half hh.
    {
      int q = wid >> 1, hh = wid & 1;
      int r = lane & 15, kb = lane >> 4;
      const short8* xg = (const short8*)xr + (size_t)(hh * 16 + r) * 176 + kb;
      f32x4 acc0 = {0.f,0.f,0.f,0.f}, acc1 = {0.f,0.f,0.f,0.f};
      int sw = ((r & 7) << 3);
      #pragma unroll
      for (int cc = 0; cc < 11; cc++){
        int ch = q * 11 + cc;
        short8 a  = xg[ch * 4];
        short8 bh = *(const short8*)(s_w1 + ((r * 1408 + ch * 32 + kb * 8) ^ sw));
        short8 bl = *(const short8*)(s_w1 + ((((16 + r) * 1408) + ch * 32 + kb * 8) ^ sw));
        acc0 = __builtin_amdgcn_mfma_f32_16x16x32_bf16(a, bh, acc0, 0, 0, 0);
        acc1 = __builtin_amdgcn_mfma_f32_16x16x32_bf16(a, bl, acc1, 0, 0, 0);
      }
      #pragma unroll
      for (int reg = 0; reg < 4; reg++){
        int b16 = kb * 4 + reg;                  // batch within half
        scrA[wid * 256 + b16 * 16 + r] = acc0[reg] + acc1[reg];
      }
      __syncthreads();
      {                                          // reduce 4 K-quarters
        int n = tid >> 4, rr = tid & 15;
        int hh2 = n >> 4, b16 = n & 15;
        float s = scrA[(0 * 2 + hh2) * 256 + b16 * 16 + rr]
                + scrA[(1 * 2 + hh2) * 256 + b16 * 16 + rr]
                + scrA[(2 * 2 + hh2) * 256 + b16 * 16 + rr]
                + scrA[(3 * 2 + hh2) * 256 + b16 * 16 + rr];
        scrB[tid] = s;
      }
      __syncthreads();
      if (tid < 128){                            // cell1: (n, unit j) per thread
        int n = tid >> 2, j = tid & 3;
        int gu = blk * 4 + j;
        float gi = scrB[n * 16 +  0 + j] + bih1[gu]          + bhh1[gu];
        float gf = scrB[n * 16 +  4 + j] + bih1[1024 + gu]   + bhh1[1024 + gu];
        float gg = scrB[n * 16 +  8 + j] + bih1[2048 + gu]   + bhh1[2048 + gu];
        float go = scrB[n * 16 + 12 + j] + bih1[3072 + gu]   + bhh1[3072 + gu];
        gi = sigf(gi); gf = sigf(gf); gg = tanhf(gg); go = sigf(go);
        int ci = n * 1024 + gu;
        float cn = gf * c1[ci] + gi * gg;
        c1[ci] = cn;
        float hn = go * tanhf(cn);
        u16 hb = f2bf(hn);
        xw[n * 1408 + 384 + gu] = hb;            // next step's input buffer
        xb2[n * 1152 + gu] = hb;                 // read by phase 2 after gbar
      }
    }
    gbar(bar, &bc);

    // ===== phase 2: gates2 (scalar fp32, weights in LDS), all 256 blocks ======
    {
      int o = tid >> 3, s = tid & 7;             // o: 2 rows x 32 batch; s: K-eighth
      int r2 = o >> 5, n = o & 31;
      const short8* xg2 = (const short8*)xb2 + n * 144 + s * 18;
      const short8* wh8 = (const short8*)s_w2 + r2 * 144 + s * 18;
      const short8* wl8 = (const short8*)s_w2 + (2 + r2) * 144 + s * 18;
      float ps = 0.f;
      #pragma unroll 3
      for (int i = 0; i < 18; i++){
        short8 x8 = xg2[i], h8 = wh8[i], l8 = wl8[i];
        #pragma unroll
        for (int e2 = 0; e2 < 8; e2++){
          float xv = bf1((u16)x8[e2]);
          float wv = bf1((u16)h8[e2]) + bf1((u16)l8[e2]);
          ps = fmaf(xv, wv, ps);
        }
      }
      scrB[o * 8 + s] = ps;
      __syncthreads();
      if (tid < 64){
        float s2 = scrB[tid * 8 + 0] + scrB[tid * 8 + 1] + scrB[tid * 8 + 2]
                 + scrB[tid * 8 + 3] + scrB[tid * 8 + 4] + scrB[tid * 8 + 5]
                 + scrB[tid * 8 + 6] + scrB[tid * 8 + 7];
        int r2b = tid >> 5, nn = tid & 31;
        gp2f[nn * 512 + blk * 2 + r2b] = s2;
      }
    }
    gbar(bar, &bc);

    // ===== phase 3: cell2 + attention + ctx + emb prefetch (blocks 0..31) =====
    if (blk < 32){
      int n = blk;
      float* s_e    = scrA;            // 512
      float* s_part = scrA + 512;      // 4 x 128
      float* s_h2   = scrB;            // 128
      float* s_red  = scrB + 128;      // 8
      float* s_scal = scrB + 136;      // 2
      if (tid < 128){
        int u = tid;
        float g0 = gp2f[n * 512 + u]       + bih2[u]       + bhh2[u];
        float g1 = gp2f[n * 512 + 128 + u] + bih2[128 + u] + bhh2[128 + u];
        float g2 = gp2f[n * 512 + 256 + u] + bih2[256 + u] + bhh2[256 + u];
        float g3 = gp2f[n * 512 + 384 + u] + bih2[384 + u] + bhh2[384 + u];
        float gi = sigf(g0), gf = sigf(g1), gt = tanhf(g2), go = sigf(g3);
        int ci = n * 128 + u;
        float cn = gf * c2[ci] + gi * gt;
        c2[ci] = cn;
        float hn = go * tanhf(cn);
        s_h2[u] = hn;
        u16 hb = f2bf(hn);
        xb2[n * 1152 + 1024 + u] = hb;
        aall[((size_t)t * NB + n) * 256 + u] = hb;
      } else if (tid < 384){
        int c = tid - 128;               // next-token embedding for step t+1
        int tok = text[n * LD + t];
        xw[n * 1408 + c] = f2bf(emb[(size_t)tok * 256 + c]);
      }
      __syncthreads();
      int el = elen[n];
      const float4* krow = (const float4*)(key + ((size_t)n * TE + tid) * 128);
      float e = 0.0f;
      #pragma unroll 8
      for (int q = 0; q < 32; q++){
        float4 w = krow[q];
        e += w.x*s_h2[4*q+0] + w.y*s_h2[4*q+1] + w.z*s_h2[4*q+2] + w.w*s_h2[4*q+3];
      }
      if (tid >= el) e = -1e9f;
      float m = e;
      for (int off = 32; off > 0; off >>= 1) m = fmaxf(m, __shfl_xor(m, off));
      if (lane == 0) s_red[wid] = m;
      __syncthreads();
      if (tid == 0){
        float mm = s_red[0];
        for (int w = 1; w < 8; w++) mm = fmaxf(mm, s_red[w]);
        s_scal[0] = mm;
      }
      __syncthreads();
      float pr = __expf(e - s_scal[0]);
      s_e[tid] = pr;
      float sm = pr;
      for (int off = 32; off > 0; off >>= 1) sm += __shfl_xor(sm, off);
      if (lane == 0) s_red[wid] = sm;
      __syncthreads();
      if (tid == 0){
        float ss = 0.0f;
        for (int w = 0; w < 8; w++) ss += s_red[w];
        s_scal[1] = ss;
      }
      __syncthreads();
      int v = tid & 127, ch = tid >> 7;
      const float* vb = values + ((size_t)n * TE + ch * 128) * 128 + v;
      float a = 0.0f;
      #pragma unroll 4
      for (int q = 0; q < 128; q++) a += s_e[ch * 128 + q] * vb[(size_t)q * 128];
      s_part[ch * 128 + v] = a;
      __syncthreads();
      if (tid < 128){
        float cv = (s_part[tid] + s_part[128 + tid] + s_part[256 + tid]
                  + s_part[384 + tid]) / s_scal[1];
        u16 cb = f2bf(cv);
        xw[n * 1408 + 256 + tid] = cb;
        aall[((size_t)t * NB + n) * 256 + 128 + tid] = cb;
      }
    }
    gbar(bar, &bc);
  }
}

// ================= output GEMM (unchanged, known-correct) =======================
__global__ __launch_bounds__(256) void k_out(
    const u16* __restrict__ aall, const float* __restrict__ wout,
    const float* __restrict__ bout, float* __restrict__ out)
{
  __shared__ __align__(16) u16 sA[128 * 136];
  __shared__ __align__(16) u16 sW[80 * 136];
  int tid = threadIdx.x;
  int vt = blockIdx.x, rt = blockIdx.y;
  int v0 = vt * 80, r0 = rt * 128;
  int rg = tid >> 4, vg = tid & 15;
  float acc[8][5];
  #pragma unroll
  for (int i = 0; i < 8; i++)
    #pragma unroll
    for (int j = 0; j < 5; j++) acc[i][j] = 0.0f;
  for (int kc = 0; kc < 2; kc++){
    int k0 = kc * 128;
    __syncthreads();
    for (int i = tid; i < 128 * 128; i += 256){
      int r = i >> 7, c = i & 127;
      sA[r * 136 + c] = aall[((size_t)(r0 + r)) * 256 + k0 + c];
    }
    for (int i = tid; i < 80 * 128; i += 256){
      int r = i >> 7, c = i & 127;
      sW[r * 136 + c] = f2bf(wout[((size_t)(v0 + r)) * 256 + k0 + c]);
    }
    __syncthreads();
    const u16* ap = sA + (rg * 8) * 136;
    const u16* wp = sW + (vg * 5) * 136;
    for (int kp = 0; kp < 64; kp++){
      u32 av[8], wv[5];
      #pragma unroll
      for (int i = 0; i < 8; i++) av[i] = *(const u32*)(ap + i * 136 + 2 * kp);
      #pragma unroll
      for (int j = 0; j < 5; j++) wv[j] = *(const u32*)(wp + j * 136 + 2 * kp);
      float wlo[5], whi[5];
      #pragma unroll
      for (int j = 0; j < 5; j++){ wlo[j] = bfl(wv[j]); whi[j] = bfh(wv[j]); }
      #pragma unroll
      for (int i = 0; i < 8; i++){
        float a0 = bfl(av[i]), a1 = bfh(av[i]);
        #pragma unroll
        for (int j = 0; j < 5; j++) acc[i][j] += a0 * wlo[j] + a1 * whi[j];
      }
    }
  }
  #pragma unroll
  for (int i = 0; i < 8; i++){
    int r = r0 + rg * 8 + i;
    int tt = r >> 5, nn = r & 31;
    size_t ob = ((size_t)nn * LD + tt) * 8000 + v0 + vg * 5;
    #pragma unroll
    for (int j = 0; j < 5; j++){
      out[ob + j] = acc[i][j] + bout[v0 + vg * 5 + j];
    }
  }
}

extern "C" void kernel_launch(void* const* d_in, const int* in_sizes, int n_in,
                              void* d_out, int out_size, void* d_ws, size_t ws_size,
                              hipStream_t stream)
{
  const float* key    = (const float*)d_in[0];
  const float* values = (const float*)d_in[1];
  const int*   elen   = (const int*)d_in[2];
  const int*   text   = (const int*)d_in[3];
  const float* emb    = (const float*)d_in[4];
  const float* Wih1   = (const float*)d_in[5];
  const float* Whh1   = (const float*)d_in[6];
  const float* bih1   = (const float*)d_in[7];
  const float* bhh1   = (const float*)d_in[8];
  const float* Wih2   = (const float*)d_in[9];
  const float* Whh2   = (const float*)d_in[10];
  const float* bih2   = (const float*)d_in[11];
  const float* bhh2   = (const float*)d_in[12];
  const float* Wout   = (const float*)d_in[13];
  const float* bout   = (const float*)d_in[14];
  float* out = (float*)d_out;
  float* ws = (float*)d_ws;

  // ---- all state in ws (~2.6 MB)
  float* c1   = ws;                         // 32768 f
  float* c2   = c1 + 32768;                 // 4096 f
  u16* xbA    = (u16*)(c2 + 4096);          // 45056 u16
  u16* xbB    = xbA + 45056;                // 45056 u16
  u16* xb2    = xbB + 45056;                // 36864 u16
  float* gp2f = (float*)(xb2 + 36864);      // 16384 f
  u16* aall   = (u16*)(gp2f + 16384);       // 1048576 u16 = 2 MB
  u32* bar    = (u32*)(aall + 1048576);

  hipMemsetAsync(bar, 0, 64, stream);

  static bool attr_set = false;
  if (!attr_set){
    hipFuncSetAttribute((const void*)k_persist,
                        hipFuncAttributeMaxDynamicSharedMemorySize, SMEM_BYTES);
    attr_set = true;
  }

  void* args[] = {
    (void*)&key, (void*)&values, (void*)&elen, (void*)&text, (void*)&emb,
    (void*)&Wih1, (void*)&Whh1, (void*)&bih1, (void*)&bhh1,
    (void*)&Wih2, (void*)&Whh2, (void*)&bih2, (void*)&bhh2,
    (void*)&xbA, (void*)&xbB, (void*)&xb2, (void*)&c1, (void*)&c2,
    (void*)&gp2f, (void*)&aall, (void*)&bar
  };
  hipLaunchCooperativeKernel((const void*)k_persist, dim3(NBLK), dim3(NTHR),
                             args, SMEM_BYTES, stream);

  k_out<<<dim3(100, 32), 256, 0, stream>>>(aall, Wout, bout, out);
}

// Round 5
// 8496.629 us; speedup vs baseline: 1.0455x; 1.0050x over previous
//
#include <hip/hip_runtime.h>

typedef unsigned short u16;
typedef unsigned int u32;
typedef unsigned long long u64;
typedef __attribute__((ext_vector_type(8))) short short8;   // 8 bf16 = 4 VGPRs (MFMA A/B frag)
typedef __attribute__((ext_vector_type(4))) float f32x4;    // MFMA C/D frag

#define NB 32
#define TE 512
#define LD 128
#define NBLK 256
#define NTHR 512
// LDS layout (dynamic, 107.0 KB):
//   s_w1 : 45056 u16 (16 rows x 1408 x {hi,lo})   [0, 90112)
//   s_w2 :  4608 u16 (2 rows x 1152 x {hi,lo})    [90112, 99328)
//   scrA :  2048 f32                              [99328, 107520)
//   scrB :   512 f32                              [107520, 109568)
#define SMEM_BYTES 109568

__device__ __forceinline__ float bfl(u32 u){ return __uint_as_float(u << 16); }
__device__ __forceinline__ float bfh(u32 u){ return __uint_as_float(u & 0xffff0000u); }
__device__ __forceinline__ float bf1(u16 v){ return __uint_as_float(((u32)v) << 16); }
__device__ __forceinline__ u16 f2bf(float f){
  u32 x = __float_as_uint(f);
  return (u16)((x + 0x7fffu + ((x >> 16) & 1u)) >> 16);
}
__device__ __forceinline__ float sigf(float x){ return 1.0f / (1.0f + __expf(-x)); }

// ---- device-coherent (LLC-direct, sc0 sc1) accessors for cross-block data ----
__device__ __forceinline__ short8 ald16(const u16* p){
  u64 a = __hip_atomic_load((const u64*)p,     __ATOMIC_RELAXED, __HIP_MEMORY_SCOPE_AGENT);
  u64 b = __hip_atomic_load((const u64*)p + 1, __ATOMIC_RELAXED, __HIP_MEMORY_SCOPE_AGENT);
  union { u64 u[2]; short8 v; } r;
  r.u[0] = a; r.u[1] = b;
  return r.v;
}
__device__ __forceinline__ void ast16(u16* p, u16 v){
  __hip_atomic_store(p, v, __ATOMIC_RELAXED, __HIP_MEMORY_SCOPE_AGENT);
}
__device__ __forceinline__ void astf(float* p, float v){
  __hip_atomic_store(p, v, __ATOMIC_RELAXED, __HIP_MEMORY_SCOPE_AGENT);
}
__device__ __forceinline__ float aldf(const float* p){
  return __hip_atomic_load(p, __ATOMIC_RELAXED, __HIP_MEMORY_SCOPE_AGENT);
}

// device-scope sense barrier WITHOUT acquire-invalidate: RELEASE on arrival
// orders producer stores (which are all write-through sc1); consumers read
// cross-block data with sc1 loads, so no L2 invalidate is needed -> L2 stays
// warm (key/values/weights) across barriers and steps. Trailing __syncthreads
// is the compiler/LDS fence.
__device__ __forceinline__ void gbar(u32* bar, u32* bc){
  __syncthreads();
  *bc += 1;
  if (threadIdx.x == 0){
    __hip_atomic_fetch_add(bar, 1u, __ATOMIC_RELEASE, __HIP_MEMORY_SCOPE_AGENT);
    u32 target = *bc * NBLK;
    while (__hip_atomic_load(bar, __ATOMIC_RELAXED, __HIP_MEMORY_SCOPE_AGENT) < target){
      __builtin_amdgcn_s_sleep(4);
    }
  }
  __syncthreads();
}

// ================= persistent kernel: whole decode loop, LDS-resident weights ===
// 256 blocks x 512 threads (1 block/CU). Block b owns:
//   gates1: units [4b, 4b+4) -> 16 w1 rows {gate*1024 + 4b + j}, LDS rows r=gate*4+j
//   gates2: rows {2b, 2b+1} of the 512 gates2 outputs
// xb (double-buffered) = [emb(256) | ctx(128) | h1(1024)] bf16, stride 1408.
// xb2 = [h1(1024) | h2(128)] bf16, stride 1152.
__global__ __launch_bounds__(NTHR, 1) void k_persist(
    const float* __restrict__ key, const float* __restrict__ values,
    const int* __restrict__ elen, const int* __restrict__ text,
    const float* __restrict__ emb,
    const float* __restrict__ Wih1, const float* __restrict__ Whh1,
    const float* __restrict__ bih1, const float* __restrict__ bhh1,
    const float* __restrict__ Wih2, const float* __restrict__ Whh2,
    const float* __restrict__ bih2, const float* __restrict__ bhh2,
    u16* __restrict__ xbA, u16* __restrict__ xbB, u16* __restrict__ xb2,
    float* __restrict__ c1, float* __restrict__ c2,
    float* __restrict__ gp2f, u16* __restrict__ aall,
    u32* __restrict__ bar)
{
  extern __shared__ __align__(16) char smem_raw[];
  u16* s_w1   = (u16*)smem_raw;                    // 45056 u16
  u16* s_w2   = (u16*)(smem_raw + 90112);          // 4608 u16
  float* scrA = (float*)(smem_raw + 99328);        // 2048 f32
  float* scrB = (float*)(smem_raw + 107520);       // 512 f32

  int tid = threadIdx.x;
  int blk = blockIdx.x;
  int lane = tid & 63, wid = tid >> 6;
  u32 bc = 0;

  // ---- load this block's weight slices into LDS (fp32 -> bf16 hi/lo) ----
  // w1: 16 rows x 1408. LDS u16 index (p*16+r)*1408 + c, XOR-swizzled by ((r&7)<<3)
  // so the MFMA ds_read_b128 (lane r stride 2816B) spreads across banks.
  for (int i = tid; i < 16 * 1408; i += NTHR){
    int r = i / 1408, c = i - r * 1408;
    int grow = (r >> 2) * 1024 + blk * 4 + (r & 3);
    float v = (c < 384) ? Wih1[(size_t)grow * 384 + c]
                        : Whh1[(size_t)grow * 1024 + (c - 384)];
    u16 h = f2bf(v);
    u16 l = f2bf(v - bf1(h));
    int sw = ((r & 7) << 3);
    s_w1[(r * 1408 + c) ^ sw] = h;
    s_w1[(((16 + r) * 1408) + c) ^ sw] = l;
  }
  // w2: 2 rows x 1152, plain layout (scalar broadcast reads later)
  for (int i = tid; i < 2 * 1152; i += NTHR){
    int r = i / 1152, c = i - r * 1152;
    int R = blk * 2 + r;
    float v = (c < 1024) ? Wih2[(size_t)R * 1024 + c]
                         : Whh2[(size_t)R * 128 + (c - 1024)];
    u16 h = f2bf(v);
    s_w2[r * 1152 + c] = h;
    s_w2[(2 + r) * 1152 + c] = f2bf(v - bf1(h));
  }

  // ---- global init: zero c1,c2,xb2; build xbA for t=0 (all sc1: cross-block) ----
  {
    int idx = blk * NTHR + tid;       // 131072 threads >= 118784 elements
    int i = idx;
    if (i < 32768){ astf(c1 + i, 0.0f); }
    else {
      i -= 32768;
      if (i < 4096){ astf(c2 + i, 0.0f); }
      else {
        i -= 4096;
        if (i < 45056){                          // 32*1408
          int n = i / 1408, c = i - n * 1408;
          u16 v = 0;
          if (c < 256)      v = f2bf(emb[256 + c]);                       // SOS
          else if (c < 384) v = f2bf(values[(size_t)n * TE * 128 + (c - 256)]);
          ast16(xbA + i, v);
        } else {
          i -= 45056;
          if (i < 36864) ast16(xb2 + i, 0);      // h1=0, h2=0
        }
      }
    }
  }
  gbar(bar, &bc);

  for (int t = 0; t < 128; t++){
    const u16* xr = (t & 1) ? xbB : xbA;     // input vector for this step
    u16* xw = (t & 1) ? xbA : xbB;           // input vector being built for t+1

    // ===== phase 1: gates1 (MFMA, weights in LDS) + cell1, all 256 blocks =====
    // wave (q = wid>>1, hh = wid&1): K-quarter q (11 chunks of 32), batch-half hh.
    {
      int q = wid >> 1, hh = wid & 1;
      int r = lane & 15, kb = lane >> 4;
      const u16* xg = xr + (size_t)(hh * 16 + r) * 1408 + kb * 8;
      f32x4 acc0 = {0.f,0.f,0.f,0.f}, acc1 = {0.f,0.f,0.f,0.f};
      int sw = ((r & 7) << 3);
      #pragma unroll
      for (int cc = 0; cc < 11; cc++){
        int ch = q * 11 + cc;
        short8 a  = ald16(xg + ch * 32);
        short8 bh = *(const short8*)(s_w1 + ((r * 1408 + ch * 32 + kb * 8) ^ sw));
        short8 bl = *(const short8*)(s_w1 + ((((16 + r) * 1408) + ch * 32 + kb * 8) ^ sw));
        acc0 = __builtin_amdgcn_mfma_f32_16x16x32_bf16(a, bh, acc0, 0, 0, 0);
        acc1 = __builtin_amdgcn_mfma_f32_16x16x32_bf16(a, bl, acc1, 0, 0, 0);
      }
      #pragma unroll
      for (int reg = 0; reg < 4; reg++){
        int b16 = kb * 4 + reg;                  // batch within half
        scrA[wid * 256 + b16 * 16 + r] = acc0[reg] + acc1[reg];
      }
      __syncthreads();
      {                                          // reduce 4 K-quarters
        int n = tid >> 4, rr = tid & 15;
        int hh2 = n >> 4, b16 = n & 15;
        float s = scrA[(0 * 2 + hh2) * 256 + b16 * 16 + rr]
                + scrA[(1 * 2 + hh2) * 256 + b16 * 16 + rr]
                + scrA[(2 * 2 + hh2) * 256 + b16 * 16 + rr]
                + scrA[(3 * 2 + hh2) * 256 + b16 * 16 + rr];
        scrB[tid] = s;
      }
      __syncthreads();
      if (tid < 128){                            // cell1: (n, unit j) per thread
        int n = tid >> 2, j = tid & 3;
        int gu = blk * 4 + j;
        float gi = scrB[n * 16 +  0 + j] + bih1[gu]          + bhh1[gu];
        float gf = scrB[n * 16 +  4 + j] + bih1[1024 + gu]   + bhh1[1024 + gu];
        float gg = scrB[n * 16 +  8 + j] + bih1[2048 + gu]   + bhh1[2048 + gu];
        float go = scrB[n * 16 + 12 + j] + bih1[3072 + gu]   + bhh1[3072 + gu];
        gi = sigf(gi); gf = sigf(gf); gg = tanhf(gg); go = sigf(go);
        int ci = n * 1024 + gu;
        float cn = gf * c1[ci] + gi * gg;        // c1: block-private, cached
        c1[ci] = cn;
        float hn = go * tanhf(cn);
        u16 hb = f2bf(hn);
        ast16(xw + n * 1408 + 384 + gu, hb);     // next step's input buffer
        ast16(xb2 + n * 1152 + gu, hb);          // read by phase 2 after gbar
      }
    }
    gbar(bar, &bc);

    // ===== phase 2: gates2 (scalar fp32, weights in LDS), all 256 blocks ======
    {
      int o = tid >> 3, s = tid & 7;             // o: 2 rows x 32 batch; s: K-eighth
      int r2 = o >> 5, n = o & 31;
      const u16* xg2 = xb2 + n * 1152 + s * 144;
      const short8* wh8 = (const short8*)s_w2 + r2 * 144 + s * 18;
      const short8* wl8 = (const short8*)s_w2 + (2 + r2) * 144 + s * 18;
      float ps = 0.f;
      #pragma unroll 3
      for (int i = 0; i < 18; i++){
        short8 x8 = ald16(xg2 + i * 8);
        short8 h8 = wh8[i], l8 = wl8[i];
        #pragma unroll
        for (int e2 = 0; e2 < 8; e2++){
          float xv = bf1((u16)x8[e2]);
          float wv = bf1((u16)h8[e2]) + bf1((u16)l8[e2]);
          ps = fmaf(xv, wv, ps);
        }
      }
      scrB[o * 8 + s] = ps;
      __syncthreads();
      if (tid < 64){
        float s2 = scrB[tid * 8 + 0] + scrB[tid * 8 + 1] + scrB[tid * 8 + 2]
                 + scrB[tid * 8 + 3] + scrB[tid * 8 + 4] + scrB[tid * 8 + 5]
                 + scrB[tid * 8 + 6] + scrB[tid * 8 + 7];
        int r2b = tid >> 5, nn = tid & 31;
        astf(gp2f + nn * 512 + blk * 2 + r2b, s2);
      }
    }
    gbar(bar, &bc);

    // ===== phase 3: cell2 + attention + ctx + emb prefetch (blocks 0..31) =====
    if (blk < 32){
      int n = blk;
      float* s_e    = scrA;            // 512
      float* s_part = scrA + 512;      // 4 x 128
      float* s_h2   = scrB;            // 128
      float* s_red  = scrB + 128;      // 8
      float* s_scal = scrB + 136;      // 2
      if (tid < 128){
        int u = tid;
        float g0 = aldf(gp2f + n * 512 + u)       + bih2[u]       + bhh2[u];
        float g1 = aldf(gp2f + n * 512 + 128 + u) + bih2[128 + u] + bhh2[128 + u];
        float g2 = aldf(gp2f + n * 512 + 256 + u) + bih2[256 + u] + bhh2[256 + u];
        float g3 = aldf(gp2f + n * 512 + 384 + u) + bih2[384 + u] + bhh2[384 + u];
        float gi = sigf(g0), gf = sigf(g1), gt = tanhf(g2), go = sigf(g3);
        int ci = n * 128 + u;
        float cn = gf * c2[ci] + gi * gt;        // c2: block-private, cached
        c2[ci] = cn;
        float hn = go * tanhf(cn);
        s_h2[u] = hn;
        u16 hb = f2bf(hn);
        ast16(xb2 + n * 1152 + 1024 + u, hb);
        aall[((size_t)t * NB + n) * 256 + u] = hb;
      } else if (tid < 384){
        int c = tid - 128;               // next-token embedding for step t+1
        int tok = text[n * LD + t];
        ast16(xw + n * 1408 + c, f2bf(emb[(size_t)tok * 256 + c]));
      }
      __syncthreads();
      int el = elen[n];
      const float4* krow = (const float4*)(key + ((size_t)n * TE + tid) * 128);
      float e = 0.0f;
      #pragma unroll 8
      for (int q = 0; q < 32; q++){
        float4 w = krow[q];
        e += w.x*s_h2[4*q+0] + w.y*s_h2[4*q+1] + w.z*s_h2[4*q+2] + w.w*s_h2[4*q+3];
      }
      if (tid >= el) e = -1e9f;
      float m = e;
      for (int off = 32; off > 0; off >>= 1) m = fmaxf(m, __shfl_xor(m, off));
      if (lane == 0) s_red[wid] = m;
      __syncthreads();
      if (tid == 0){
        float mm = s_red[0];
        for (int w = 1; w < 8; w++) mm = fmaxf(mm, s_red[w]);
        s_scal[0] = mm;
      }
      __syncthreads();
      float pr = __expf(e - s_scal[0]);
      s_e[tid] = pr;
      float sm = pr;
      for (int off = 32; off > 0; off >>= 1) sm += __shfl_xor(sm, off);
      if (lane == 0) s_red[wid] = sm;
      __syncthreads();
      if (tid == 0){
        float ss = 0.0f;
        for (int w = 0; w < 8; w++) ss += s_red[w];
        s_scal[1] = ss;
      }
      __syncthreads();
      int v = tid & 127, ch = tid >> 7;
      const float* vb = values + ((size_t)n * TE + ch * 128) * 128 + v;
      float a = 0.0f;
      #pragma unroll 4
      for (int q = 0; q < 128; q++) a += s_e[ch * 128 + q] * vb[(size_t)q * 128];
      s_part[ch * 128 + v] = a;
      __syncthreads();
      if (tid < 128){
        float cv = (s_part[tid] + s_part[128 + tid] + s_part[256 + tid]
                  + s_part[384 + tid]) / s_scal[1];
        u16 cb = f2bf(cv);
        ast16(xw + n * 1408 + 256 + tid, cb);
        aall[((size_t)t * NB + n) * 256 + 128 + tid] = cb;
      }
    }
    gbar(bar, &bc);
  }
}

// ================= output GEMM (unchanged, known-correct) =======================
__global__ __launch_bounds__(256) void k_out(
    const u16* __restrict__ aall, const float* __restrict__ wout,
    const float* __restrict__ bout, float* __restrict__ out)
{
  __shared__ __align__(16) u16 sA[128 * 136];
  __shared__ __align__(16) u16 sW[80 * 136];
  int tid = threadIdx.x;
  int vt = blockIdx.x, rt = blockIdx.y;
  int v0 = vt * 80, r0 = rt * 128;
  int rg = tid >> 4, vg = tid & 15;
  float acc[8][5];
  #pragma unroll
  for (int i = 0; i < 8; i++)
    #pragma unroll
    for (int j = 0; j < 5; j++) acc[i][j] = 0.0f;
  for (int kc = 0; kc < 2; kc++){
    int k0 = kc * 128;
    __syncthreads();
    for (int i = tid; i < 128 * 128; i += 256){
      int r = i >> 7, c = i & 127;
      sA[r * 136 + c] = aall[((size_t)(r0 + r)) * 256 + k0 + c];
    }
    for (int i = tid; i < 80 * 128; i += 256){
      int r = i >> 7, c = i & 127;
      sW[r * 136 + c] = f2bf(wout[((size_t)(v0 + r)) * 256 + k0 + c]);
    }
    __syncthreads();
    const u16* ap = sA + (rg * 8) * 136;
    const u16* wp = sW + (vg * 5) * 136;
    for (int kp = 0; kp < 64; kp++){
      u32 av[8], wv[5];
      #pragma unroll
      for (int i = 0; i < 8; i++) av[i] = *(const u32*)(ap + i * 136 + 2 * kp);
      #pragma unroll
      for (int j = 0; j < 5; j++) wv[j] = *(const u32*)(wp + j * 136 + 2 * kp);
      float wlo[5], whi[5];
      #pragma unroll
      for (int j = 0; j < 5; j++){ wlo[j] = bfl(wv[j]); whi[j] = bfh(wv[j]); }
      #pragma unroll
      for (int i = 0; i < 8; i++){
        float a0 = bfl(av[i]), a1 = bfh(av[i]);
        #pragma unroll
        for (int j = 0; j < 5; j++) acc[i][j] += a0 * wlo[j] + a1 * whi[j];
      }
    }
  }
  #pragma unroll
  for (int i = 0; i < 8; i++){
    int r = r0 + rg * 8 + i;
    int tt = r >> 5, nn = r & 31;
    size_t ob = ((size_t)nn * LD + tt) * 8000 + v0 + vg * 5;
    #pragma unroll
    for (int j = 0; j < 5; j++){
      out[ob + j] = acc[i][j] + bout[v0 + vg * 5 + j];
    }
  }
}

extern "C" void kernel_launch(void* const* d_in, const int* in_sizes, int n_in,
                              void* d_out, int out_size, void* d_ws, size_t ws_size,
                              hipStream_t stream)
{
  const float* key    = (const float*)d_in[0];
  const float* values = (const float*)d_in[1];
  const int*   elen   = (const int*)d_in[2];
  const int*   text   = (const int*)d_in[3];
  const float* emb    = (const float*)d_in[4];
  const float* Wih1   = (const float*)d_in[5];
  const float* Whh1   = (const float*)d_in[6];
  const float* bih1   = (const float*)d_in[7];
  const float* bhh1   = (const float*)d_in[8];
  const float* Wih2   = (const float*)d_in[9];
  const float* Whh2   = (const float*)d_in[10];
  const float* bih2   = (const float*)d_in[11];
  const float* bhh2   = (const float*)d_in[12];
  const float* Wout   = (const float*)d_in[13];
  const float* bout   = (const float*)d_in[14];
  float* out = (float*)d_out;
  float* ws = (float*)d_ws;

  // ---- all state in ws (~2.6 MB)
  float* c1   = ws;                         // 32768 f
  float* c2   = c1 + 32768;                 // 4096 f
  u16* xbA    = (u16*)(c2 + 4096);          // 45056 u16
  u16* xbB    = xbA + 45056;                // 45056 u16
  u16* xb2    = xbB + 45056;                // 36864 u16
  float* gp2f = (float*)(xb2 + 36864);      // 16384 f
  u16* aall   = (u16*)(gp2f + 16384);       // 1048576 u16 = 2 MB
  u32* bar    = (u32*)(aall + 1048576);

  hipMemsetAsync(bar, 0, 64, stream);

  static bool attr_set = false;
  if (!attr_set){
    hipFuncSetAttribute((const void*)k_persist,
                        hipFuncAttributeMaxDynamicSharedMemorySize, SMEM_BYTES);
    attr_set = true;
  }

  void* args[] = {
    (void*)&key, (void*)&values, (void*)&elen, (void*)&text, (void*)&emb,
    (void*)&Wih1, (void*)&Whh1, (void*)&bih1, (void*)&bhh1,
    (void*)&Wih2, (void*)&Whh2, (void*)&bih2, (void*)&bhh2,
    (void*)&xbA, (void*)&xbB, (void*)&xb2, (void*)&c1, (void*)&c2,
    (void*)&gp2f, (void*)&aall, (void*)&bar
  };
  hipLaunchCooperativeKernel((const void*)k_persist, dim3(NBLK), dim3(NTHR),
                             args, SMEM_BYTES, stream);

  k_out<<<dim3(100, 32), 256, 0, stream>>>(aall, Wout, bout, out);
}